// Round 4
// baseline (452.906 us; speedup 1.0000x reference)
//
#include <hip/hip_runtime.h>
#include <math.h>

#define Bq 8
#define Sq 4096
#define Hq 4096
#define NHq 32
#define KVHq 8
#define HDq 128
#define QKV_N 6144   // NH*HD + 2*KVH*HD
#define CHUNK 256
#define NCHUNK 16    // S / CHUNK
#define ROWS 128     // split-K row chunk for gemv

// Generic: y[b*ldY + col] += sum_r x[b*K + r] * W[r*ldW + col]  over rows [blockIdx.y*ROWS, +ROWS)
__global__ __launch_bounds__(256) void gemv_splitk(
    const float* __restrict__ x, const float* __restrict__ W,
    float* __restrict__ y, int K, int ldW, int ldY) {
  __shared__ float xs[Bq][ROWS];
  int tid = threadIdx.x;
  int r0 = blockIdx.y * ROWS;
  for (int i = tid; i < Bq * ROWS; i += 256) {
    int b = i >> 7, r = i & (ROWS - 1);
    xs[b][r] = x[b * K + r0 + r];
  }
  __syncthreads();
  int col = blockIdx.x * 256 + tid;
  float acc[Bq] = {0, 0, 0, 0, 0, 0, 0, 0};
  const float* wp = W + (size_t)r0 * ldW + col;
  for (int r = 0; r < ROWS; r += 16) {
    float w[16];
#pragma unroll
    for (int j = 0; j < 16; j++) w[j] = wp[(size_t)j * ldW];
    wp += (size_t)16 * ldW;
#pragma unroll
    for (int b = 0; b < Bq; b++) {
      float4 x0 = *(const float4*)&xs[b][r];
      float4 x1 = *(const float4*)&xs[b][r + 4];
      float4 x2 = *(const float4*)&xs[b][r + 8];
      float4 x3 = *(const float4*)&xs[b][r + 12];
      acc[b] = fmaf(x0.x, w[0], acc[b]);
      acc[b] = fmaf(x0.y, w[1], acc[b]);
      acc[b] = fmaf(x0.z, w[2], acc[b]);
      acc[b] = fmaf(x0.w, w[3], acc[b]);
      acc[b] = fmaf(x1.x, w[4], acc[b]);
      acc[b] = fmaf(x1.y, w[5], acc[b]);
      acc[b] = fmaf(x1.z, w[6], acc[b]);
      acc[b] = fmaf(x1.w, w[7], acc[b]);
      acc[b] = fmaf(x2.x, w[8], acc[b]);
      acc[b] = fmaf(x2.y, w[9], acc[b]);
      acc[b] = fmaf(x2.z, w[10], acc[b]);
      acc[b] = fmaf(x2.w, w[11], acc[b]);
      acc[b] = fmaf(x3.x, w[12], acc[b]);
      acc[b] = fmaf(x3.y, w[13], acc[b]);
      acc[b] = fmaf(x3.z, w[14], acc[b]);
      acc[b] = fmaf(x3.w, w[15], acc[b]);
    }
  }
#pragma unroll
  for (int b = 0; b < Bq; b++) atomicAdd(&y[b * ldY + col], acc[b]);
}

// Fused QKV projection: columns 0..4095 -> q_w, 4096..5119 -> k_w, 5120..6143 -> v_w.
__global__ __launch_bounds__(256) void gemv_fused_qkv(
    const float* __restrict__ x, const float* __restrict__ qw,
    const float* __restrict__ kw, const float* __restrict__ vw,
    float* __restrict__ y) {
  __shared__ float xs[Bq][ROWS];
  int tid = threadIdx.x;
  int r0 = blockIdx.y * ROWS;
  for (int i = tid; i < Bq * ROWS; i += 256) {
    int b = i >> 7, r = i & (ROWS - 1);
    xs[b][r] = x[b * Hq + r0 + r];
  }
  __syncthreads();
  int col = blockIdx.x * 256 + tid;
  const float* W;
  int ldW, wcol;
  if (col < NHq * HDq) { W = qw; ldW = NHq * HDq; wcol = col; }
  else if (col < NHq * HDq + KVHq * HDq) { W = kw; ldW = KVHq * HDq; wcol = col - NHq * HDq; }
  else { W = vw; ldW = KVHq * HDq; wcol = col - (NHq + KVHq) * HDq; }
  float acc[Bq] = {0, 0, 0, 0, 0, 0, 0, 0};
  const float* wp = W + (size_t)r0 * ldW + wcol;
  for (int r = 0; r < ROWS; r += 16) {
    float w[16];
#pragma unroll
    for (int j = 0; j < 16; j++) w[j] = wp[(size_t)j * ldW];
    wp += (size_t)16 * ldW;
#pragma unroll
    for (int b = 0; b < Bq; b++) {
      float4 x0 = *(const float4*)&xs[b][r];
      float4 x1 = *(const float4*)&xs[b][r + 4];
      float4 x2 = *(const float4*)&xs[b][r + 8];
      float4 x3 = *(const float4*)&xs[b][r + 12];
      acc[b] = fmaf(x0.x, w[0], acc[b]);
      acc[b] = fmaf(x0.y, w[1], acc[b]);
      acc[b] = fmaf(x0.z, w[2], acc[b]);
      acc[b] = fmaf(x0.w, w[3], acc[b]);
      acc[b] = fmaf(x1.x, w[4], acc[b]);
      acc[b] = fmaf(x1.y, w[5], acc[b]);
      acc[b] = fmaf(x1.z, w[6], acc[b]);
      acc[b] = fmaf(x1.w, w[7], acc[b]);
      acc[b] = fmaf(x2.x, w[8], acc[b]);
      acc[b] = fmaf(x2.y, w[9], acc[b]);
      acc[b] = fmaf(x2.z, w[10], acc[b]);
      acc[b] = fmaf(x2.w, w[11], acc[b]);
      acc[b] = fmaf(x3.x, w[12], acc[b]);
      acc[b] = fmaf(x3.y, w[13], acc[b]);
      acc[b] = fmaf(x3.z, w[14], acc[b]);
      acc[b] = fmaf(x3.w, w[15], acc[b]);
    }
  }
#pragma unroll
  for (int b = 0; b < Bq; b++) atomicAdd(&y[b * QKV_N + col], acc[b]);
}

// One wave per vector: 256 q vectors (rmsnorm+rope -> qvec), 64 k vectors
// (rmsnorm+rope -> key_cache[step]), 64 v vectors (copy -> value_cache[step]).
__global__ __launch_bounds__(256) void normrope(
    const float* __restrict__ qkv, const float* __restrict__ cosp,
    const float* __restrict__ sinp, const float* __restrict__ qnw,
    const float* __restrict__ knw, const int* __restrict__ step_ptr,
    float* __restrict__ kcache, float* __restrict__ vcache,
    float* __restrict__ qvec) {
  int tid = threadIdx.x;
  int lane = tid & 63, wid = tid >> 6;
  int vec = blockIdx.x * 4 + wid;  // 0..383
  int step = *step_ptr;
  if (vec < 256) {  // q heads
    int b = vec >> 5, h = vec & 31;
    const float* src = qkv + b * QKV_N + h * HDq;
    float x0 = src[lane], x1 = src[lane + 64];
    float ss = fmaf(x0, x0, x1 * x1);
#pragma unroll
    for (int off = 32; off; off >>= 1) ss += __shfl_xor(ss, off, 64);
    float sc = rsqrtf(ss * (1.0f / HDq) + 1e-6f);
    float n0 = x0 * sc * qnw[lane], n1 = x1 * sc * qnw[lane + 64];
    float c0 = cosp[b * HDq + lane], c1 = cosp[b * HDq + lane + 64];
    float s0 = sinp[b * HDq + lane], s1 = sinp[b * HDq + lane + 64];
    float* dst = qvec + b * (NHq * HDq) + h * HDq;
    dst[lane] = fmaf(n0, c0, -n1 * s0);
    dst[lane + 64] = fmaf(n1, c1, n0 * s1);
  } else if (vec < 320) {  // k heads
    int v = vec - 256;
    int b = v >> 3, kvh = v & 7;
    const float* src = qkv + b * QKV_N + NHq * HDq + kvh * HDq;
    float x0 = src[lane], x1 = src[lane + 64];
    float ss = fmaf(x0, x0, x1 * x1);
#pragma unroll
    for (int off = 32; off; off >>= 1) ss += __shfl_xor(ss, off, 64);
    float sc = rsqrtf(ss * (1.0f / HDq) + 1e-6f);
    float n0 = x0 * sc * knw[lane], n1 = x1 * sc * knw[lane + 64];
    float c0 = cosp[b * HDq + lane], c1 = cosp[b * HDq + lane + 64];
    float s0 = sinp[b * HDq + lane], s1 = sinp[b * HDq + lane + 64];
    float* dst = kcache + (((size_t)(b * KVHq + kvh)) * Sq + step) * HDq;
    dst[lane] = fmaf(n0, c0, -n1 * s0);
    dst[lane + 64] = fmaf(n1, c1, n0 * s1);
  } else {  // v heads
    int v = vec - 320;
    int b = v >> 3, kvh = v & 7;
    const float* src = qkv + b * QKV_N + (NHq + KVHq) * HDq + kvh * HDq;
    float* dst = vcache + (((size_t)(b * KVHq + kvh)) * Sq + step) * HDq;
    dst[lane] = src[lane];
    dst[lane + 64] = src[lane + 64];
  }
}

// Flash-decode partial: grid (NCHUNK, B*KVH). Each block: 4 GQA heads x 256 positions.
// QK: thread->position, 16 float4 K loads in flight.
// PV: thread->(d-quad, s-group), coalesced float4 V loads, LDS tree-reduce.
__global__ __launch_bounds__(256) void attn_partial(
    const float* __restrict__ qvec, const float* __restrict__ kc,
    const float* __restrict__ vc, const int* __restrict__ step_ptr,
    float* __restrict__ pm, float* __restrict__ pl, float* __restrict__ po) {
  int c = blockIdx.x;
  int bk = blockIdx.y;  // b*KVH + kvh
  int b = bk >> 3, kvh = bk & 7;
  int step = *step_ptr;
  int base = c * CHUNK;
  int pidx = (bk * NCHUNK + c) * 4;
  int tid = threadIdx.x;
  if (base > step) {
    if (tid < 4) { pm[pidx + tid] = -1e38f; pl[pidx + tid] = 0.0f; }
    return;
  }
  __shared__ float qs[4][HDq];
  __shared__ float red[4][4];
  __shared__ float pls[4][CHUNK];
  __shared__ float4 ored[8][4][32];  // 16 KB: s-group x head x d-quad
  for (int i = tid; i < 4 * HDq; i += 256)
    qs[i >> 7][i & 127] = qvec[b * (NHq * HDq) + (kvh * 4 + (i >> 7)) * HDq + (i & 127)];
  __syncthreads();

  // ---- QK^T: each thread owns one position s, full 128-d dot for 4 heads ----
  int s = base + tid;
  const float* krow = kc + (((size_t)bk) * Sq + s) * HDq;
  float sc[4] = {0, 0, 0, 0};
#pragma unroll
  for (int dd = 0; dd < HDq; dd += 64) {
    float4 kk[16];
#pragma unroll
    for (int j = 0; j < 16; j++) kk[j] = *(const float4*)(krow + dd + j * 4);
#pragma unroll
    for (int j = 0; j < 16; j++) {
#pragma unroll
      for (int g = 0; g < 4; g++) {
        float4 qq = *(const float4*)&qs[g][dd + j * 4];
        sc[g] = fmaf(kk[j].x, qq.x, sc[g]);
        sc[g] = fmaf(kk[j].y, qq.y, sc[g]);
        sc[g] = fmaf(kk[j].z, qq.z, sc[g]);
        sc[g] = fmaf(kk[j].w, qq.w, sc[g]);
      }
    }
  }
  const float scaling = 0.08838834764831845f;  // 1/sqrt(128)
  bool valid = (s <= step);
#pragma unroll
  for (int g = 0; g < 4; g++) sc[g] = valid ? sc[g] * scaling : -1e30f;

  // ---- prefetch first V batch (addresses independent of softmax) ----
  int q4 = tid & 31, grp = tid >> 5;  // d-quad, s-group of 32
  const float* vb = vc + (((size_t)bk) * Sq + base + grp * 32) * HDq + q4 * 4;
  float4 vpre[8];
#pragma unroll
  for (int j = 0; j < 8; j++) vpre[j] = *(const float4*)(vb + (size_t)j * HDq);

  // ---- softmax (max, exp, sum) ----
  int lane = tid & 63, wid = tid >> 6;
#pragma unroll
  for (int g = 0; g < 4; g++) {
    float v = sc[g];
#pragma unroll
    for (int off = 32; off; off >>= 1) v = fmaxf(v, __shfl_xor(v, off, 64));
    if (lane == 0) red[g][wid] = v;
  }
  __syncthreads();
  float m[4];
#pragma unroll
  for (int g = 0; g < 4; g++)
    m[g] = fmaxf(fmaxf(red[g][0], red[g][1]), fmaxf(red[g][2], red[g][3]));
  __syncthreads();
#pragma unroll
  for (int g = 0; g < 4; g++) {
    float p = __expf(sc[g] - m[g]);  // invalid lanes underflow to 0
    pls[g][tid] = p;
    float v = p;
#pragma unroll
    for (int off = 32; off; off >>= 1) v += __shfl_xor(v, off, 64);
    if (lane == 0) red[g][wid] = v;
  }
  __syncthreads();
  if (tid < 4) {
    pm[pidx + tid] = m[tid];
    pl[pidx + tid] = red[tid][0] + red[tid][1] + red[tid][2] + red[tid][3];
  }

  // ---- PV: o[g][d] = sum_s p[g][s] * V[s][d] ----
  float4 o[4];
#pragma unroll
  for (int g = 0; g < 4; g++) { o[g].x = 0; o[g].y = 0; o[g].z = 0; o[g].w = 0; }
#pragma unroll
  for (int j = 0; j < 8; j++) {
#pragma unroll
    for (int g = 0; g < 4; g++) {
      float p = pls[g][grp * 32 + j];
      o[g].x = fmaf(p, vpre[j].x, o[g].x);
      o[g].y = fmaf(p, vpre[j].y, o[g].y);
      o[g].z = fmaf(p, vpre[j].z, o[g].z);
      o[g].w = fmaf(p, vpre[j].w, o[g].w);
    }
  }
  for (int ss = 8; ss < 32; ss += 8) {
    float4 vv[8];
#pragma unroll
    for (int j = 0; j < 8; j++) vv[j] = *(const float4*)(vb + (size_t)(ss + j) * HDq);
#pragma unroll
    for (int j = 0; j < 8; j++) {
#pragma unroll
      for (int g = 0; g < 4; g++) {
        float p = pls[g][grp * 32 + ss + j];
        o[g].x = fmaf(p, vv[j].x, o[g].x);
        o[g].y = fmaf(p, vv[j].y, o[g].y);
        o[g].z = fmaf(p, vv[j].z, o[g].z);
        o[g].w = fmaf(p, vv[j].w, o[g].w);
      }
    }
  }
#pragma unroll
  for (int g = 0; g < 4; g++) ored[grp][g][q4] = o[g];
  __syncthreads();
  if (tid < 128) {
    int g = tid >> 5, q = tid & 31;
    float4 sum = ored[0][g][q];
#pragma unroll
    for (int r = 1; r < 8; r++) {
      float4 t = ored[r][g][q];
      sum.x += t.x; sum.y += t.y; sum.z += t.z; sum.w += t.w;
    }
    *(float4*)&po[(size_t)(pidx + g) * HDq + q * 4] = sum;
  }
}

__global__ __launch_bounds__(128) void attn_combine(
    const float* __restrict__ pm, const float* __restrict__ pl,
    const float* __restrict__ po, float* __restrict__ aout) {
  int bh = blockIdx.x;  // 0..255
  int b = bh >> 5, h = bh & 31;
  int kvh = h >> 2, g = h & 3;
  int d = threadIdx.x;
  int bk = b * KVHq + kvh;
  float mv[NCHUNK];
  float M = -1e38f;
#pragma unroll
  for (int c = 0; c < NCHUNK; c++) {
    mv[c] = pm[(bk * NCHUNK + c) * 4 + g];
    M = fmaxf(M, mv[c]);
  }
  float L = 0.0f, o = 0.0f;
#pragma unroll
  for (int c = 0; c < NCHUNK; c++) {
    if (mv[c] > -1e37f) {
      float w = __expf(mv[c] - M);
      L = fmaf(pl[(bk * NCHUNK + c) * 4 + g], w, L);
      o = fmaf(po[(size_t)((bk * NCHUNK + c) * 4 + g) * HDq + d], w, o);
    }
  }
  aout[b * (NHq * HDq) + h * HDq + d] = o / L;
}

extern "C" void kernel_launch(void* const* d_in, const int* in_sizes, int n_in,
                              void* d_out, int out_size, void* d_ws, size_t ws_size,
                              hipStream_t stream) {
  const float* hidden = (const float*)d_in[0];
  const float* cosp   = (const float*)d_in[1];
  const float* sinp   = (const float*)d_in[2];
  float* kcache       = (float*)d_in[3];
  float* vcache       = (float*)d_in[4];
  // d_in[5] causal_mask unused (mask == skip s > step; masked exp underflows to 0)
  const float* q_w    = (const float*)d_in[6];
  const float* k_w    = (const float*)d_in[7];
  const float* v_w    = (const float*)d_in[8];
  const float* o_w    = (const float*)d_in[9];
  const float* qnw    = (const float*)d_in[10];
  const float* knw    = (const float*)d_in[11];
  const int* step_ptr = (const int*)d_in[12];
  float* out = (float*)d_out;
  float* ws = (float*)d_ws;

  float* qkv  = ws;            // 8*6144 = 49152
  float* qvec = ws + 49152;    // 8*32*128 = 32768
  float* aout = ws + 81920;    // 32768
  float* pm   = ws + 114688;   // 64*16*4 = 4096
  float* pl   = ws + 118784;   // 4096
  float* po   = ws + 122880;   // 64*16*4*128 = 524288
  (void)in_sizes; (void)n_in; (void)ws_size;

  (void)hipMemsetAsync(qkv, 0, 49152 * sizeof(float), stream);
  (void)hipMemsetAsync(out, 0, (size_t)out_size * sizeof(float), stream);

  // Fused QKV projection: 6144 columns x 4096 rows, split-K over 32 row-blocks
  gemv_fused_qkv<<<dim3(QKV_N / 256, Hq / ROWS), 256, 0, stream>>>(hidden, q_w, k_w, v_w, qkv);

  normrope<<<96, 256, 0, stream>>>(qkv, cosp, sinp, qnw, knw, step_ptr, kcache, vcache, qvec);

  attn_partial<<<dim3(NCHUNK, Bq * KVHq), 256, 0, stream>>>(qvec, kcache, vcache, step_ptr, pm, pl, po);
  attn_combine<<<Bq * NHq, 128, 0, stream>>>(pm, pl, po, aout);

  // Output projection
  gemv_splitk<<<dim3(16, Hq / ROWS), 256, 0, stream>>>(aout, o_w, out, NHq * HDq, 4096, 4096);
}

// Round 6
// 429.767 us; speedup vs baseline: 1.0538x; 1.0538x over previous
//
#include <hip/hip_runtime.h>
#include <math.h>

#define Bq 8
#define Sq 4096
#define Hq 4096
#define NHq 32
#define KVHq 8
#define HDq 128
#define QKV_N 6144   // NH*HD + 2*KVH*HD
#define CHUNK 256
#define NCHUNK 16    // S / CHUNK
#define ROWS 128     // split-K row chunk for gemv

// Generic: y[b*ldY + col] += sum_r x[b*K + r] * W[r*ldW + col]  over rows [blockIdx.y*ROWS, +ROWS)
__global__ __launch_bounds__(256) void gemv_splitk(
    const float* __restrict__ x, const float* __restrict__ W,
    float* __restrict__ y, int K, int ldW, int ldY) {
  __shared__ float xs[Bq][ROWS];
  int tid = threadIdx.x;
  int r0 = blockIdx.y * ROWS;
  for (int i = tid; i < Bq * ROWS; i += 256) {
    int b = i >> 7, r = i & (ROWS - 1);
    xs[b][r] = x[b * K + r0 + r];
  }
  __syncthreads();
  int col = blockIdx.x * 256 + tid;
  float acc[Bq] = {0, 0, 0, 0, 0, 0, 0, 0};
  const float* wp = W + (size_t)r0 * ldW + col;
  for (int r = 0; r < ROWS; r += 16) {
    float w[16];
#pragma unroll
    for (int j = 0; j < 16; j++) w[j] = wp[(size_t)j * ldW];
    wp += (size_t)16 * ldW;
#pragma unroll
    for (int b = 0; b < Bq; b++) {
      float4 x0 = *(const float4*)&xs[b][r];
      float4 x1 = *(const float4*)&xs[b][r + 4];
      float4 x2 = *(const float4*)&xs[b][r + 8];
      float4 x3 = *(const float4*)&xs[b][r + 12];
      acc[b] = fmaf(x0.x, w[0], acc[b]);
      acc[b] = fmaf(x0.y, w[1], acc[b]);
      acc[b] = fmaf(x0.z, w[2], acc[b]);
      acc[b] = fmaf(x0.w, w[3], acc[b]);
      acc[b] = fmaf(x1.x, w[4], acc[b]);
      acc[b] = fmaf(x1.y, w[5], acc[b]);
      acc[b] = fmaf(x1.z, w[6], acc[b]);
      acc[b] = fmaf(x1.w, w[7], acc[b]);
      acc[b] = fmaf(x2.x, w[8], acc[b]);
      acc[b] = fmaf(x2.y, w[9], acc[b]);
      acc[b] = fmaf(x2.z, w[10], acc[b]);
      acc[b] = fmaf(x2.w, w[11], acc[b]);
      acc[b] = fmaf(x3.x, w[12], acc[b]);
      acc[b] = fmaf(x3.y, w[13], acc[b]);
      acc[b] = fmaf(x3.z, w[14], acc[b]);
      acc[b] = fmaf(x3.w, w[15], acc[b]);
    }
  }
#pragma unroll
  for (int b = 0; b < Bq; b++) atomicAdd(&y[b * ldY + col], acc[b]);
}

// Fused QKV projection: columns 0..4095 -> q_w, 4096..5119 -> k_w, 5120..6143 -> v_w.
__global__ __launch_bounds__(256) void gemv_fused_qkv(
    const float* __restrict__ x, const float* __restrict__ qw,
    const float* __restrict__ kw, const float* __restrict__ vw,
    float* __restrict__ y) {
  __shared__ float xs[Bq][ROWS];
  int tid = threadIdx.x;
  int r0 = blockIdx.y * ROWS;
  for (int i = tid; i < Bq * ROWS; i += 256) {
    int b = i >> 7, r = i & (ROWS - 1);
    xs[b][r] = x[b * Hq + r0 + r];
  }
  __syncthreads();
  int col = blockIdx.x * 256 + tid;
  const float* W;
  int ldW, wcol;
  if (col < NHq * HDq) { W = qw; ldW = NHq * HDq; wcol = col; }
  else if (col < NHq * HDq + KVHq * HDq) { W = kw; ldW = KVHq * HDq; wcol = col - NHq * HDq; }
  else { W = vw; ldW = KVHq * HDq; wcol = col - (NHq + KVHq) * HDq; }
  float acc[Bq] = {0, 0, 0, 0, 0, 0, 0, 0};
  const float* wp = W + (size_t)r0 * ldW + wcol;
  for (int r = 0; r < ROWS; r += 16) {
    float w[16];
#pragma unroll
    for (int j = 0; j < 16; j++) w[j] = wp[(size_t)j * ldW];
    wp += (size_t)16 * ldW;
#pragma unroll
    for (int b = 0; b < Bq; b++) {
      float4 x0 = *(const float4*)&xs[b][r];
      float4 x1 = *(const float4*)&xs[b][r + 4];
      float4 x2 = *(const float4*)&xs[b][r + 8];
      float4 x3 = *(const float4*)&xs[b][r + 12];
      acc[b] = fmaf(x0.x, w[0], acc[b]);
      acc[b] = fmaf(x0.y, w[1], acc[b]);
      acc[b] = fmaf(x0.z, w[2], acc[b]);
      acc[b] = fmaf(x0.w, w[3], acc[b]);
      acc[b] = fmaf(x1.x, w[4], acc[b]);
      acc[b] = fmaf(x1.y, w[5], acc[b]);
      acc[b] = fmaf(x1.z, w[6], acc[b]);
      acc[b] = fmaf(x1.w, w[7], acc[b]);
      acc[b] = fmaf(x2.x, w[8], acc[b]);
      acc[b] = fmaf(x2.y, w[9], acc[b]);
      acc[b] = fmaf(x2.z, w[10], acc[b]);
      acc[b] = fmaf(x2.w, w[11], acc[b]);
      acc[b] = fmaf(x3.x, w[12], acc[b]);
      acc[b] = fmaf(x3.y, w[13], acc[b]);
      acc[b] = fmaf(x3.z, w[14], acc[b]);
      acc[b] = fmaf(x3.w, w[15], acc[b]);
    }
  }
#pragma unroll
  for (int b = 0; b < Bq; b++) atomicAdd(&y[b * QKV_N + col], acc[b]);
}

// One wave per vector: 256 q vectors (rmsnorm+rope -> qvec), 64 k vectors
// (rmsnorm+rope -> key_cache[step]), 64 v vectors (copy -> value_cache[step]).
__global__ __launch_bounds__(256) void normrope(
    const float* __restrict__ qkv, const float* __restrict__ cosp,
    const float* __restrict__ sinp, const float* __restrict__ qnw,
    const float* __restrict__ knw, const int* __restrict__ step_ptr,
    float* __restrict__ kcache, float* __restrict__ vcache,
    float* __restrict__ qvec) {
  int tid = threadIdx.x;
  int lane = tid & 63, wid = tid >> 6;
  int vec = blockIdx.x * 4 + wid;  // 0..383
  int step = *step_ptr;
  if (vec < 256) {  // q heads
    int b = vec >> 5, h = vec & 31;
    const float* src = qkv + b * QKV_N + h * HDq;
    float x0 = src[lane], x1 = src[lane + 64];
    float ss = fmaf(x0, x0, x1 * x1);
#pragma unroll
    for (int off = 32; off; off >>= 1) ss += __shfl_xor(ss, off, 64);
    float sc = rsqrtf(ss * (1.0f / HDq) + 1e-6f);
    float n0 = x0 * sc * qnw[lane], n1 = x1 * sc * qnw[lane + 64];
    float c0 = cosp[b * HDq + lane], c1 = cosp[b * HDq + lane + 64];
    float s0 = sinp[b * HDq + lane], s1 = sinp[b * HDq + lane + 64];
    float* dst = qvec + b * (NHq * HDq) + h * HDq;
    dst[lane] = fmaf(n0, c0, -n1 * s0);
    dst[lane + 64] = fmaf(n1, c1, n0 * s1);
  } else if (vec < 320) {  // k heads
    int v = vec - 256;
    int b = v >> 3, kvh = v & 7;
    const float* src = qkv + b * QKV_N + NHq * HDq + kvh * HDq;
    float x0 = src[lane], x1 = src[lane + 64];
    float ss = fmaf(x0, x0, x1 * x1);
#pragma unroll
    for (int off = 32; off; off >>= 1) ss += __shfl_xor(ss, off, 64);
    float sc = rsqrtf(ss * (1.0f / HDq) + 1e-6f);
    float n0 = x0 * sc * knw[lane], n1 = x1 * sc * knw[lane + 64];
    float c0 = cosp[b * HDq + lane], c1 = cosp[b * HDq + lane + 64];
    float s0 = sinp[b * HDq + lane], s1 = sinp[b * HDq + lane + 64];
    float* dst = kcache + (((size_t)(b * KVHq + kvh)) * Sq + step) * HDq;
    dst[lane] = fmaf(n0, c0, -n1 * s0);
    dst[lane + 64] = fmaf(n1, c1, n0 * s1);
  } else {  // v heads
    int v = vec - 320;
    int b = v >> 3, kvh = v & 7;
    const float* src = qkv + b * QKV_N + (NHq + KVHq) * HDq + kvh * HDq;
    float* dst = vcache + (((size_t)(b * KVHq + kvh)) * Sq + step) * HDq;
    dst[lane] = src[lane];
    dst[lane + 64] = src[lane + 64];
  }
}

// Flash-decode partial: grid (NCHUNK, B*KVH). Each block: 4 GQA heads x 256 positions.
// QK: thread->position, 8 float4 K loads in flight per batch.
// PV: thread->(d-quad, s-group), coalesced float4 V loads (8 in flight), LDS tree-reduce.
__global__ __launch_bounds__(256) void attn_partial(
    const float* __restrict__ qvec, const float* __restrict__ kc,
    const float* __restrict__ vc, const int* __restrict__ step_ptr,
    float* __restrict__ pm, float* __restrict__ pl, float* __restrict__ po) {
  int c = blockIdx.x;
  int bk = blockIdx.y;  // b*KVH + kvh
  int b = bk >> 3, kvh = bk & 7;
  int step = *step_ptr;
  int base = c * CHUNK;
  int pidx = (bk * NCHUNK + c) * 4;
  int tid = threadIdx.x;
  if (base > step) {
    if (tid < 4) { pm[pidx + tid] = -1e38f; pl[pidx + tid] = 0.0f; }
    return;
  }
  __shared__ float qs[4][HDq];
  __shared__ float red[4][4];
  __shared__ float pls[4][CHUNK];
  __shared__ float4 ored[8][4][32];  // 16 KB: s-group x head x d-quad
  for (int i = tid; i < 4 * HDq; i += 256)
    qs[i >> 7][i & 127] = qvec[b * (NHq * HDq) + (kvh * 4 + (i >> 7)) * HDq + (i & 127)];
  __syncthreads();

  // ---- QK^T: each thread owns one position s, full 128-d dot for 4 heads ----
  int s = base + tid;
  const float* krow = kc + (((size_t)bk) * Sq + s) * HDq;
  float sc[4] = {0, 0, 0, 0};
#pragma unroll
  for (int dd = 0; dd < HDq; dd += 32) {
    float4 kk[8];
#pragma unroll
    for (int j = 0; j < 8; j++) kk[j] = *(const float4*)(krow + dd + j * 4);
#pragma unroll
    for (int j = 0; j < 8; j++) {
#pragma unroll
      for (int g = 0; g < 4; g++) {
        float4 qq = *(const float4*)&qs[g][dd + j * 4];
        sc[g] = fmaf(kk[j].x, qq.x, sc[g]);
        sc[g] = fmaf(kk[j].y, qq.y, sc[g]);
        sc[g] = fmaf(kk[j].z, qq.z, sc[g]);
        sc[g] = fmaf(kk[j].w, qq.w, sc[g]);
      }
    }
  }
  const float scaling = 0.08838834764831845f;  // 1/sqrt(128)
  bool valid = (s <= step);
#pragma unroll
  for (int g = 0; g < 4; g++) sc[g] = valid ? sc[g] * scaling : -1e30f;

  // ---- softmax (max, exp, sum) ----
  int lane = tid & 63, wid = tid >> 6;
#pragma unroll
  for (int g = 0; g < 4; g++) {
    float v = sc[g];
#pragma unroll
    for (int off = 32; off; off >>= 1) v = fmaxf(v, __shfl_xor(v, off, 64));
    if (lane == 0) red[g][wid] = v;
  }
  __syncthreads();
  float m[4];
#pragma unroll
  for (int g = 0; g < 4; g++)
    m[g] = fmaxf(fmaxf(red[g][0], red[g][1]), fmaxf(red[g][2], red[g][3]));
  __syncthreads();
#pragma unroll
  for (int g = 0; g < 4; g++) {
    float p = __expf(sc[g] - m[g]);  // invalid lanes underflow to 0
    pls[g][tid] = p;
    float v = p;
#pragma unroll
    for (int off = 32; off; off >>= 1) v += __shfl_xor(v, off, 64);
    if (lane == 0) red[g][wid] = v;
  }
  __syncthreads();
  if (tid < 4) {
    pm[pidx + tid] = m[tid];
    pl[pidx + tid] = red[tid][0] + red[tid][1] + red[tid][2] + red[tid][3];
  }

  // ---- PV: o[g][d] = sum_s p[g][s] * V[s][d] ----
  int q4 = tid & 31, grp = tid >> 5;  // d-quad, s-group of 32
  const float* vb = vc + (((size_t)bk) * Sq + base + grp * 32) * HDq + q4 * 4;
  float4 o[4];
#pragma unroll
  for (int g = 0; g < 4; g++) { o[g].x = 0; o[g].y = 0; o[g].z = 0; o[g].w = 0; }
  for (int ss = 0; ss < 32; ss += 8) {
    float4 vv[8];
#pragma unroll
    for (int j = 0; j < 8; j++) vv[j] = *(const float4*)(vb + (size_t)(ss + j) * HDq);
#pragma unroll
    for (int j = 0; j < 8; j++) {
#pragma unroll
      for (int g = 0; g < 4; g++) {
        float p = pls[g][grp * 32 + ss + j];
        o[g].x = fmaf(p, vv[j].x, o[g].x);
        o[g].y = fmaf(p, vv[j].y, o[g].y);
        o[g].z = fmaf(p, vv[j].z, o[g].z);
        o[g].w = fmaf(p, vv[j].w, o[g].w);
      }
    }
  }
#pragma unroll
  for (int g = 0; g < 4; g++) ored[grp][g][q4] = o[g];
  __syncthreads();
  if (tid < 128) {
    int g = tid >> 5, q = tid & 31;
    float4 sum = ored[0][g][q];
#pragma unroll
    for (int r = 1; r < 8; r++) {
      float4 t = ored[r][g][q];
      sum.x += t.x; sum.y += t.y; sum.z += t.z; sum.w += t.w;
    }
    *(float4*)&po[(size_t)(pidx + g) * HDq + q * 4] = sum;
  }
}

__global__ __launch_bounds__(128) void attn_combine(
    const float* __restrict__ pm, const float* __restrict__ pl,
    const float* __restrict__ po, float* __restrict__ aout) {
  int bh = blockIdx.x;  // 0..255
  int b = bh >> 5, h = bh & 31;
  int kvh = h >> 2, g = h & 3;
  int d = threadIdx.x;
  int bk = b * KVHq + kvh;
  float mv[NCHUNK];
  float M = -1e38f;
#pragma unroll
  for (int c = 0; c < NCHUNK; c++) {
    mv[c] = pm[(bk * NCHUNK + c) * 4 + g];
    M = fmaxf(M, mv[c]);
  }
  float L = 0.0f, o = 0.0f;
#pragma unroll
  for (int c = 0; c < NCHUNK; c++) {
    if (mv[c] > -1e37f) {
      float w = __expf(mv[c] - M);
      L = fmaf(pl[(bk * NCHUNK + c) * 4 + g], w, L);
      o = fmaf(po[(size_t)((bk * NCHUNK + c) * 4 + g) * HDq + d], w, o);
    }
  }
  aout[b * (NHq * HDq) + h * HDq + d] = o / L;
}

extern "C" void kernel_launch(void* const* d_in, const int* in_sizes, int n_in,
                              void* d_out, int out_size, void* d_ws, size_t ws_size,
                              hipStream_t stream) {
  const float* hidden = (const float*)d_in[0];
  const float* cosp   = (const float*)d_in[1];
  const float* sinp   = (const float*)d_in[2];
  float* kcache       = (float*)d_in[3];
  float* vcache       = (float*)d_in[4];
  // d_in[5] causal_mask unused (mask == skip s > step; masked exp underflows to 0)
  const float* q_w    = (const float*)d_in[6];
  const float* k_w    = (const float*)d_in[7];
  const float* v_w    = (const float*)d_in[8];
  const float* o_w    = (const float*)d_in[9];
  const float* qnw    = (const float*)d_in[10];
  const float* knw    = (const float*)d_in[11];
  const int* step_ptr = (const int*)d_in[12];
  float* out = (float*)d_out;
  float* ws = (float*)d_ws;

  float* qkv  = ws;            // 8*6144 = 49152
  float* qvec = ws + 49152;    // 8*32*128 = 32768
  float* aout = ws + 81920;    // 32768
  float* pm   = ws + 114688;   // 64*16*4 = 4096
  float* pl   = ws + 118784;   // 4096
  float* po   = ws + 122880;   // 64*16*4*128 = 524288
  (void)in_sizes; (void)n_in; (void)ws_size;

  (void)hipMemsetAsync(qkv, 0, 49152 * sizeof(float), stream);
  (void)hipMemsetAsync(out, 0, (size_t)out_size * sizeof(float), stream);

  // Fused QKV projection: 6144 columns x 4096 rows, split-K over 32 row-blocks
  gemv_fused_qkv<<<dim3(QKV_N / 256, Hq / ROWS), 256, 0, stream>>>(hidden, q_w, k_w, v_w, qkv);

  normrope<<<96, 256, 0, stream>>>(qkv, cosp, sinp, qnw, knw, step_ptr, kcache, vcache, qvec);

  attn_partial<<<dim3(NCHUNK, Bq * KVHq), 256, 0, stream>>>(qvec, kcache, vcache, step_ptr, pm, pl, po);
  attn_combine<<<Bq * NHq, 128, 0, stream>>>(pm, pl, po, aout);

  // Output projection
  gemv_splitk<<<dim3(16, Hq / ROWS), 256, 0, stream>>>(aout, o_w, out, NHq * HDq, 4096, 4096);
}

// Round 7
// 403.662 us; speedup vs baseline: 1.1220x; 1.0647x over previous
//
#include <hip/hip_runtime.h>
#include <math.h>

#define Bq 8
#define Sq 4096
#define Hq 4096
#define NHq 32
#define KVHq 8
#define HDq 128
#define QKV_N 6144   // NH*HD + 2*KVH*HD
#define CHUNK 256
#define NCHUNK 16    // S / CHUNK
#define ROWS 128     // split-K row chunk for gemv

// y[b*ldY + col] += sum_r x[b*K + r] * W[r*ldW + col]  over rows [blockIdx.y*ROWS, +ROWS)
// x values are wave-uniform -> scalar (SGPR) loads; no LDS staging.
__global__ __launch_bounds__(256) void gemv_splitk(
    const float* __restrict__ x, const float* __restrict__ W,
    float* __restrict__ y, int K, int ldW, int ldY) {
  int tid = threadIdx.x;
  int r0 = blockIdx.y * ROWS;
  int col = blockIdx.x * 256 + tid;
  float acc[Bq] = {0, 0, 0, 0, 0, 0, 0, 0};
  const float* wp = W + (size_t)r0 * ldW + col;
  const float* xp = x + r0;
  for (int r = 0; r < ROWS; r += 16) {
    float w[16];
#pragma unroll
    for (int j = 0; j < 16; j++) w[j] = wp[(size_t)j * ldW];
    wp += (size_t)16 * ldW;
#pragma unroll
    for (int b = 0; b < Bq; b++) {
      const float* xb = xp + b * K + r;
#pragma unroll
      for (int j = 0; j < 16; j++) acc[b] = fmaf(xb[j], w[j], acc[b]);
    }
  }
#pragma unroll
  for (int b = 0; b < Bq; b++) atomicAdd(&y[b * ldY + col], acc[b]);
}

// Fused QKV projection: columns 0..4095 -> q_w, 4096..5119 -> k_w, 5120..6143 -> v_w.
// Column ranges are block-uniform (256 cols per block), so W selection is wave-uniform.
__global__ __launch_bounds__(256) void gemv_fused_qkv(
    const float* __restrict__ x, const float* __restrict__ qw,
    const float* __restrict__ kw, const float* __restrict__ vw,
    float* __restrict__ y) {
  int tid = threadIdx.x;
  int r0 = blockIdx.y * ROWS;
  int col = blockIdx.x * 256 + tid;
  const float* W;
  int ldW, wcol;
  if (col < NHq * HDq) { W = qw; ldW = NHq * HDq; wcol = col; }
  else if (col < NHq * HDq + KVHq * HDq) { W = kw; ldW = KVHq * HDq; wcol = col - NHq * HDq; }
  else { W = vw; ldW = KVHq * HDq; wcol = col - (NHq + KVHq) * HDq; }
  float acc[Bq] = {0, 0, 0, 0, 0, 0, 0, 0};
  const float* wp = W + (size_t)r0 * ldW + wcol;
  const float* xp = x + r0;
  for (int r = 0; r < ROWS; r += 16) {
    float w[16];
#pragma unroll
    for (int j = 0; j < 16; j++) w[j] = wp[(size_t)j * ldW];
    wp += (size_t)16 * ldW;
#pragma unroll
    for (int b = 0; b < Bq; b++) {
      const float* xb = xp + b * Hq + r;
#pragma unroll
      for (int j = 0; j < 16; j++) acc[b] = fmaf(xb[j], w[j], acc[b]);
    }
  }
#pragma unroll
  for (int b = 0; b < Bq; b++) atomicAdd(&y[b * QKV_N + col], acc[b]);
}

// One wave per vector: 256 q vectors (rmsnorm+rope -> qvec), 64 k vectors
// (rmsnorm+rope -> key_cache[step]), 64 v vectors (copy -> value_cache[step]).
__global__ __launch_bounds__(256) void normrope(
    const float* __restrict__ qkv, const float* __restrict__ cosp,
    const float* __restrict__ sinp, const float* __restrict__ qnw,
    const float* __restrict__ knw, const int* __restrict__ step_ptr,
    float* __restrict__ kcache, float* __restrict__ vcache,
    float* __restrict__ qvec) {
  int tid = threadIdx.x;
  int lane = tid & 63, wid = tid >> 6;
  int vec = blockIdx.x * 4 + wid;  // 0..383
  int step = *step_ptr;
  if (vec < 256) {  // q heads
    int b = vec >> 5, h = vec & 31;
    const float* src = qkv + b * QKV_N + h * HDq;
    float x0 = src[lane], x1 = src[lane + 64];
    float ss = fmaf(x0, x0, x1 * x1);
#pragma unroll
    for (int off = 32; off; off >>= 1) ss += __shfl_xor(ss, off, 64);
    float sc = rsqrtf(ss * (1.0f / HDq) + 1e-6f);
    float n0 = x0 * sc * qnw[lane], n1 = x1 * sc * qnw[lane + 64];
    float c0 = cosp[b * HDq + lane], c1 = cosp[b * HDq + lane + 64];
    float s0 = sinp[b * HDq + lane], s1 = sinp[b * HDq + lane + 64];
    float* dst = qvec + b * (NHq * HDq) + h * HDq;
    dst[lane] = fmaf(n0, c0, -n1 * s0);
    dst[lane + 64] = fmaf(n1, c1, n0 * s1);
  } else if (vec < 320) {  // k heads
    int v = vec - 256;
    int b = v >> 3, kvh = v & 7;
    const float* src = qkv + b * QKV_N + NHq * HDq + kvh * HDq;
    float x0 = src[lane], x1 = src[lane + 64];
    float ss = fmaf(x0, x0, x1 * x1);
#pragma unroll
    for (int off = 32; off; off >>= 1) ss += __shfl_xor(ss, off, 64);
    float sc = rsqrtf(ss * (1.0f / HDq) + 1e-6f);
    float n0 = x0 * sc * knw[lane], n1 = x1 * sc * knw[lane + 64];
    float c0 = cosp[b * HDq + lane], c1 = cosp[b * HDq + lane + 64];
    float s0 = sinp[b * HDq + lane], s1 = sinp[b * HDq + lane + 64];
    float* dst = kcache + (((size_t)(b * KVHq + kvh)) * Sq + step) * HDq;
    dst[lane] = fmaf(n0, c0, -n1 * s0);
    dst[lane + 64] = fmaf(n1, c1, n0 * s1);
  } else {  // v heads
    int v = vec - 320;
    int b = v >> 3, kvh = v & 7;
    const float* src = qkv + b * QKV_N + (NHq + KVHq) * HDq + kvh * HDq;
    float* dst = vcache + (((size_t)(b * KVHq + kvh)) * Sq + step) * HDq;
    dst[lane] = src[lane];
    dst[lane + 64] = src[lane + 64];
  }
}

// Flash-decode partial: grid (NCHUNK, B*KVH). Each block: 4 GQA heads x 256 positions.
// QK: thread->position, 8 float4 K loads per batch, unroll 1 (cap VGPR).
// PV: thread->(d-quad, s-group), coalesced float4 V loads, unroll 1, LDS tree-reduce.
__global__ __launch_bounds__(256) void attn_partial(
    const float* __restrict__ qvec, const float* __restrict__ kc,
    const float* __restrict__ vc, const int* __restrict__ step_ptr,
    float* __restrict__ pm, float* __restrict__ pl, float* __restrict__ po) {
  int c = blockIdx.x;
  int bk = blockIdx.y;  // b*KVH + kvh
  int b = bk >> 3, kvh = bk & 7;
  int step = *step_ptr;
  int base = c * CHUNK;
  int pidx = (bk * NCHUNK + c) * 4;
  int tid = threadIdx.x;
  if (base > step) {
    if (tid < 4) { pm[pidx + tid] = -1e38f; pl[pidx + tid] = 0.0f; }
    return;
  }
  __shared__ float qs[4][HDq];
  __shared__ float red[4][4];
  __shared__ float pls[4][CHUNK];
  __shared__ float4 ored[8][4][32];  // 16 KB: s-group x head x d-quad
  for (int i = tid; i < 4 * HDq; i += 256)
    qs[i >> 7][i & 127] = qvec[b * (NHq * HDq) + (kvh * 4 + (i >> 7)) * HDq + (i & 127)];
  __syncthreads();

  // ---- QK^T: each thread owns one position s, full 128-d dot for 4 heads ----
  int s = base + tid;
  const float* krow = kc + (((size_t)bk) * Sq + s) * HDq;
  float sc[4] = {0, 0, 0, 0};
#pragma unroll 1
  for (int dd = 0; dd < HDq; dd += 32) {
    float4 kk[8];
#pragma unroll
    for (int j = 0; j < 8; j++) kk[j] = *(const float4*)(krow + dd + j * 4);
#pragma unroll
    for (int j = 0; j < 8; j++) {
#pragma unroll
      for (int g = 0; g < 4; g++) {
        float4 qq = *(const float4*)&qs[g][dd + j * 4];
        sc[g] = fmaf(kk[j].x, qq.x, sc[g]);
        sc[g] = fmaf(kk[j].y, qq.y, sc[g]);
        sc[g] = fmaf(kk[j].z, qq.z, sc[g]);
        sc[g] = fmaf(kk[j].w, qq.w, sc[g]);
      }
    }
  }
  const float scaling = 0.08838834764831845f;  // 1/sqrt(128)
  bool valid = (s <= step);
#pragma unroll
  for (int g = 0; g < 4; g++) sc[g] = valid ? sc[g] * scaling : -1e30f;

  // ---- softmax (max, exp, sum) ----
  int lane = tid & 63, wid = tid >> 6;
#pragma unroll
  for (int g = 0; g < 4; g++) {
    float v = sc[g];
#pragma unroll
    for (int off = 32; off; off >>= 1) v = fmaxf(v, __shfl_xor(v, off, 64));
    if (lane == 0) red[g][wid] = v;
  }
  __syncthreads();
  float m[4];
#pragma unroll
  for (int g = 0; g < 4; g++)
    m[g] = fmaxf(fmaxf(red[g][0], red[g][1]), fmaxf(red[g][2], red[g][3]));
  __syncthreads();
#pragma unroll
  for (int g = 0; g < 4; g++) {
    float p = __expf(sc[g] - m[g]);  // invalid lanes underflow to 0
    pls[g][tid] = p;
    float v = p;
#pragma unroll
    for (int off = 32; off; off >>= 1) v += __shfl_xor(v, off, 64);
    if (lane == 0) red[g][wid] = v;
  }
  __syncthreads();
  if (tid < 4) {
    pm[pidx + tid] = m[tid];
    pl[pidx + tid] = red[tid][0] + red[tid][1] + red[tid][2] + red[tid][3];
  }

  // ---- PV: o[g][d] = sum_s p[g][s] * V[s][d] ----
  int q4 = tid & 31, grp = tid >> 5;  // d-quad, s-group of 32
  const float* vb = vc + (((size_t)bk) * Sq + base + grp * 32) * HDq + q4 * 4;
  float4 o[4];
#pragma unroll
  for (int g = 0; g < 4; g++) { o[g].x = 0; o[g].y = 0; o[g].z = 0; o[g].w = 0; }
#pragma unroll 1
  for (int ss = 0; ss < 32; ss += 8) {
    float4 vv[8];
#pragma unroll
    for (int j = 0; j < 8; j++) vv[j] = *(const float4*)(vb + (size_t)(ss + j) * HDq);
#pragma unroll
    for (int j = 0; j < 8; j++) {
#pragma unroll
      for (int g = 0; g < 4; g++) {
        float p = pls[g][grp * 32 + ss + j];
        o[g].x = fmaf(p, vv[j].x, o[g].x);
        o[g].y = fmaf(p, vv[j].y, o[g].y);
        o[g].z = fmaf(p, vv[j].z, o[g].z);
        o[g].w = fmaf(p, vv[j].w, o[g].w);
      }
    }
  }
#pragma unroll
  for (int g = 0; g < 4; g++) ored[grp][g][q4] = o[g];
  __syncthreads();
  if (tid < 128) {
    int g = tid >> 5, q = tid & 31;
    float4 sum = ored[0][g][q];
#pragma unroll
    for (int r = 1; r < 8; r++) {
      float4 t = ored[r][g][q];
      sum.x += t.x; sum.y += t.y; sum.z += t.z; sum.w += t.w;
    }
    *(float4*)&po[(size_t)(pidx + g) * HDq + q * 4] = sum;
  }
}

__global__ __launch_bounds__(128) void attn_combine(
    const float* __restrict__ pm, const float* __restrict__ pl,
    const float* __restrict__ po, float* __restrict__ aout) {
  int bh = blockIdx.x;  // 0..255
  int b = bh >> 5, h = bh & 31;
  int kvh = h >> 2, g = h & 3;
  int d = threadIdx.x;
  int bk = b * KVHq + kvh;
  float mv[NCHUNK];
  float M = -1e38f;
#pragma unroll
  for (int c = 0; c < NCHUNK; c++) {
    mv[c] = pm[(bk * NCHUNK + c) * 4 + g];
    M = fmaxf(M, mv[c]);
  }
  float L = 0.0f, o = 0.0f;
#pragma unroll
  for (int c = 0; c < NCHUNK; c++) {
    if (mv[c] > -1e37f) {
      float w = __expf(mv[c] - M);
      L = fmaf(pl[(bk * NCHUNK + c) * 4 + g], w, L);
      o = fmaf(po[(size_t)((bk * NCHUNK + c) * 4 + g) * HDq + d], w, o);
    }
  }
  aout[b * (NHq * HDq) + h * HDq + d] = o / L;
}

extern "C" void kernel_launch(void* const* d_in, const int* in_sizes, int n_in,
                              void* d_out, int out_size, void* d_ws, size_t ws_size,
                              hipStream_t stream) {
  const float* hidden = (const float*)d_in[0];
  const float* cosp   = (const float*)d_in[1];
  const float* sinp   = (const float*)d_in[2];
  float* kcache       = (float*)d_in[3];
  float* vcache       = (float*)d_in[4];
  // d_in[5] causal_mask unused (mask == skip s > step; masked exp underflows to 0)
  const float* q_w    = (const float*)d_in[6];
  const float* k_w    = (const float*)d_in[7];
  const float* v_w    = (const float*)d_in[8];
  const float* o_w    = (const float*)d_in[9];
  const float* qnw    = (const float*)d_in[10];
  const float* knw    = (const float*)d_in[11];
  const int* step_ptr = (const int*)d_in[12];
  float* out = (float*)d_out;
  float* ws = (float*)d_ws;

  float* qkv  = ws;            // 8*6144 = 49152
  float* qvec = ws + 49152;    // 8*32*128 = 32768
  float* aout = ws + 81920;    // 32768
  float* pm   = ws + 114688;   // 64*16*4 = 4096
  float* pl   = ws + 118784;   // 4096
  float* po   = ws + 122880;   // 64*16*4*128 = 524288
  (void)in_sizes; (void)n_in; (void)ws_size;

  (void)hipMemsetAsync(qkv, 0, 49152 * sizeof(float), stream);
  (void)hipMemsetAsync(out, 0, (size_t)out_size * sizeof(float), stream);

  // Fused QKV projection: 6144 columns x 4096 rows, split-K over 32 row-blocks
  gemv_fused_qkv<<<dim3(QKV_N / 256, Hq / ROWS), 256, 0, stream>>>(hidden, q_w, k_w, v_w, qkv);

  normrope<<<96, 256, 0, stream>>>(qkv, cosp, sinp, qnw, knw, step_ptr, kcache, vcache, qvec);

  attn_partial<<<dim3(NCHUNK, Bq * KVHq), 256, 0, stream>>>(qvec, kcache, vcache, step_ptr, pm, pl, po);
  attn_combine<<<Bq * NHq, 128, 0, stream>>>(pm, pl, po, aout);

  // Output projection
  gemv_splitk<<<dim3(16, Hq / ROWS), 256, 0, stream>>>(aout, o_w, out, NHq * HDq, 4096, 4096);
}